// Round 1
// baseline (377.120 us; speedup 1.0000x reference)
//
#include <hip/hip_runtime.h>
#include <cstddef>

// Problem constants
constexpr int NB = 8;      // batch
constexpr int NV = 6;      // views (scan length)
constexpr int NS = 32;     // stochastic dim S
constexpr int ND = 128;    // deter dim D
constexpr int NH = 128;    // hidden H
constexpr int NOBS = 768;  // obs dim

// -------- Kernel 0: mask prep (detect int32 vs byte bool layout) --------
__global__ void prep_mask(const void* cam, float* maskf) {
    if (threadIdx.x != 0 || blockIdx.x != 0) return;
    const int* wi = (const int*)cam;
    bool is_i32 = true;
    for (int i = 0; i < NB * NV; i++) {
        unsigned v = (unsigned)wi[i];
        if (v > 1u) { is_i32 = false; break; }
    }
    const unsigned char* wb = (const unsigned char*)cam;
    for (int b = 0; b < NB; b++)
        for (int v = 0; v < NV; v++) {
            int val = is_i32 ? wi[b * NV + v] : (int)wb[b * NV + v];
            maskf[v * NB + b] = val ? 1.0f : 0.0f;   // mask_T layout (V,B)
        }
}

// -------- Kernel 1: feature means (the HBM-bound part) --------
// One 64-lane wave per (b,v,channel) job. Writes obs/tgt in (V,B,768) layout.
__global__ __launch_bounds__(256) void reduce_feats(
    const float* __restrict__ sf0, const float* __restrict__ sf1,
    const float* __restrict__ tf0, const float* __restrict__ tf1,
    float* __restrict__ obs, float* __restrict__ tgt)
{
    const int NF0 = NB * NV * 256;  // 12288 channels per tensor
    const int NF1 = NB * NV * 512;  // 24576
    int wid = (blockIdx.x * blockDim.x + threadIdx.x) >> 6;
    int lane = threadIdx.x & 63;

    const float* src;
    float* dst;
    int nvec;
    float inv;
    if (wid < 2 * NF0) {
        bool stu = wid < NF0;
        int jj = stu ? wid : wid - NF0;
        src = (stu ? sf0 : tf0) + (size_t)jj * 2816;   // 32*88
        int b = jj / (NV * 256);
        int r = jj % (NV * 256);
        int v = r >> 8;
        int c = r & 255;
        dst = (stu ? obs : tgt) + ((size_t)(v * NB + b)) * NOBS + c;
        nvec = 704;               // 2816/4
        inv = 1.0f / 2816.0f;
    } else {
        int k = wid - 2 * NF0;
        if (k >= 2 * NF1) return;
        bool stu = k < NF1;
        int jj = stu ? k : k - NF1;
        src = (stu ? sf1 : tf1) + (size_t)jj * 704;    // 16*44
        int b = jj / (NV * 512);
        int r = jj % (NV * 512);
        int v = r >> 9;
        int c = r & 511;
        dst = (stu ? obs : tgt) + ((size_t)(v * NB + b)) * NOBS + 256 + c;
        nvec = 176;               // 704/4
        inv = 1.0f / 704.0f;
    }
    const float4* s4 = (const float4*)src;
    float sum = 0.0f;
    for (int k = lane; k < nvec; k += 64) {
        float4 x = s4[k];
        sum += x.x + x.y + x.z + x.w;
    }
    for (int o = 32; o > 0; o >>= 1) sum += __shfl_down(sum, o);
    if (lane == 0) *dst = sum * inv;
}

// -------- Kernel 2: encoder for all 48 (v,b) rows in parallel --------
__global__ __launch_bounds__(128) void encoder(
    const float* __restrict__ obs,
    const float* __restrict__ w1, const float* __restrict__ b1,
    const float* __restrict__ g, const float* __restrict__ be,
    const float* __restrict__ w2, const float* __restrict__ b2,
    float* __restrict__ obs_embed)
{
    __shared__ float xs[NOBS];
    __shared__ float hs[NH];
    __shared__ float red[2];
    int r = blockIdx.x;       // r = v*NB + b
    int tid = threadIdx.x;    // 0..127
    const float* row = obs + (size_t)r * NOBS;
    for (int i = tid; i < NOBS; i += 128) xs[i] = row[i];
    __syncthreads();

    float acc = b1[tid];
    for (int i = 0; i < NOBS; i++) acc += xs[i] * w1[i * NH + tid];

    // LayerNorm over 128
    float vsum = acc;
    for (int o = 32; o > 0; o >>= 1) vsum += __shfl_down(vsum, o);
    if ((tid & 63) == 0) red[tid >> 6] = vsum;
    __syncthreads();
    float mu = (red[0] + red[1]) * (1.0f / 128.0f);
    float d = acc - mu;
    float dv = d * d;
    __syncthreads();
    for (int o = 32; o > 0; o >>= 1) dv += __shfl_down(dv, o);
    if ((tid & 63) == 0) red[tid >> 6] = dv;
    __syncthreads();
    float var = (red[0] + red[1]) * (1.0f / 128.0f);

    float xn = d * rsqrtf(var + 1e-5f) * g[tid] + be[tid];
    float h1 = xn / (1.0f + expf(-xn));   // silu
    hs[tid] = h1;
    __syncthreads();

    float a2 = b2[tid];
    for (int i = 0; i < NH; i++) a2 += hs[i] * w2[i * NH + tid];
    float oe = a2 / (1.0f + expf(-a2));
    obs_embed[(size_t)r * NH + tid] = oe;
}

// -------- Kernel 3: RSSM scan, one block per batch row --------
__global__ __launch_bounds__(256) void rssm_scan(
    const float* __restrict__ obs_embed, const float* __restrict__ tgt,
    const float* __restrict__ maskf,
    const float* __restrict__ eps_prior, const float* __restrict__ eps_post,
    const float* __restrict__ prior_w1, const float* __restrict__ prior_b1,
    const float* __restrict__ prior_w2, const float* __restrict__ prior_b2,
    const float* __restrict__ post_w1, const float* __restrict__ post_b1,
    const float* __restrict__ post_w2, const float* __restrict__ post_b2,
    const float* __restrict__ dec_w1, const float* __restrict__ dec_b1,
    const float* __restrict__ dec_w2, const float* __restrict__ dec_b2,
    const float* __restrict__ gru_wih, const float* __restrict__ gru_whh,
    const float* __restrict__ gru_bih, const float* __restrict__ gru_bhh,
    float* __restrict__ recon_out, float* __restrict__ kl_out)
{
    int b = blockIdx.x;       // 0..7
    int tid = threadIdx.x;    // 0..255

    __shared__ float deter[ND], obs_e[NH], t1[NH], t2[NH];
    __shared__ float pmu[NS], plv[NS], qmu[NS], qlv[NS], zs[NS];
    __shared__ float gi[3 * ND], gh[3 * ND], d1[NH], redbuf[4];

    if (tid < ND) deter[tid] = 0.0f;
    __syncthreads();

    for (int t = 0; t < NV; t++) {
        int rb = t * NB + b;
        if (tid < NH) obs_e[tid] = obs_embed[(size_t)rb * NH + tid];
        __syncthreads();

        // prior hidden (tid<128) | post hidden (tid>=128), both only need deter/obs_e
        if (tid < NH) {
            float a = prior_b1[tid];
            for (int i = 0; i < ND; i++) a += deter[i] * prior_w1[i * NH + tid];
            t1[tid] = a / (1.0f + expf(-a));
        } else {
            int j = tid - 128;
            float a = post_b1[j];
            for (int i = 0; i < ND; i++) a += deter[i] * post_w1[i * NH + j];
            for (int i = 0; i < NH; i++) a += obs_e[i] * post_w1[(ND + i) * NH + j];
            t2[j] = a / (1.0f + expf(-a));
        }
        __syncthreads();

        // second layers: prior out (tid<64) | post out (64<=tid<128)
        if (tid < 64) {
            float a = prior_b2[tid];
            for (int i = 0; i < NH; i++) a += t1[i] * prior_w2[i * 64 + tid];
            if (tid < NS) pmu[tid] = a; else plv[tid - NS] = a;
        } else if (tid < 128) {
            int j = tid - 64;
            float a = post_b2[j];
            for (int i = 0; i < NH; i++) a += t2[i] * post_w2[i * 64 + j];
            if (j < NS) qmu[j] = a; else qlv[j - NS] = a;
        }
        __syncthreads();

        // z sample
        if (tid < NS) {
            float m = maskf[rb];
            float epr = eps_prior[(size_t)rb * NS + tid];
            float epo = eps_post[(size_t)rb * NS + tid];
            float zp = pmu[tid] + epr * expf(0.5f * plv[tid]);
            float zq = qmu[tid] + epo * expf(0.5f * qlv[tid]);
            zs[tid] = (m > 0.0f) ? zp : zq;
        }
        __syncthreads();

        // kl for this (t,b) -- tiny, one thread while others start GRU
        if (tid == 0) {
            float s = 0.0f;
            for (int i = 0; i < NS; i++) {
                float vq = fmaxf(expf(qlv[i]), 1e-5f);
                float vp = fmaxf(expf(plv[i]), 1e-5f);
                float dm = qmu[i] - pmu[i];
                s += 0.5f * ((vq + dm * dm) / vp - 1.0f + plv[i] - qlv[i]);
            }
            kl_out[rb] = s;
        }

        // GRU gates
        for (int j = tid; j < 3 * ND; j += 256) {
            float a = gru_bih[j];
            for (int s = 0; s < NS; s++) a += zs[s] * gru_wih[s * (3 * ND) + j];
            gi[j] = a;
            float h = gru_bhh[j];
            for (int i = 0; i < ND; i++) h += deter[i] * gru_whh[i * (3 * ND) + j];
            gh[j] = h;
        }
        __syncthreads();

        float dnew = 0.0f;
        if (tid < ND) {
            float r = 1.0f / (1.0f + expf(-(gi[tid] + gh[tid])));
            float u = 1.0f / (1.0f + expf(-(gi[ND + tid] + gh[ND + tid])));
            float n = tanhf(gi[2 * ND + tid] + r * gh[2 * ND + tid]);
            dnew = (1.0f - u) * n + u * deter[tid];
        }
        __syncthreads();
        if (tid < ND) deter[tid] = dnew;
        __syncthreads();

        // decoder layer 1: din = [deter, z]
        if (tid < NH) {
            float a = dec_b1[tid];
            for (int i = 0; i < ND; i++) a += deter[i] * dec_w1[i * NH + tid];
            for (int s = 0; s < NS; s++) a += zs[s] * dec_w1[(ND + s) * NH + tid];
            d1[tid] = a / (1.0f + expf(-a));
        }
        __syncthreads();

        // decoder layer 2 + recon MSE
        float se = 0.0f;
        const float* trow = tgt + (size_t)rb * NOBS;
        for (int o = tid; o < NOBS; o += 256) {
            float a = dec_b2[o];
            for (int i = 0; i < NH; i++) a += d1[i] * dec_w2[i * NOBS + o];
            float df = a - trow[o];
            se += df * df;
        }
        for (int o2 = 32; o2 > 0; o2 >>= 1) se += __shfl_down(se, o2);
        if ((tid & 63) == 0) redbuf[tid >> 6] = se;
        __syncthreads();
        if (tid == 0)
            recon_out[rb] = (redbuf[0] + redbuf[1] + redbuf[2] + redbuf[3]) * (1.0f / 768.0f);
        __syncthreads();
    }
}

// -------- Kernel 4: finalize (mask-weighted scalar combine) --------
__global__ void finalize(const float* __restrict__ maskf,
                         const float* __restrict__ recon,
                         const float* __restrict__ kl,
                         float* __restrict__ out)
{
    if (threadIdx.x != 0 || blockIdx.x != 0) return;
    float rl = 0.0f, rs = 0.0f, ka = 0.0f, kn = 0.0f;
    for (int t = 0; t < NV; t++) {
        float ms = 0.0f, rsum = 0.0f, osum = 0.0f, ksum = 0.0f;
        for (int b = 0; b < NB; b++) {
            float m = maskf[t * NB + b];
            ms += m;
            rsum += recon[t * NB + b] * m;
            osum += 1.0f - m;
            ksum += kl[t * NB + b] * (1.0f - m);
        }
        if (ms > 0.0f) { rl += rsum / fmaxf(ms, 1.0f); rs += 1.0f; }
        if (osum > 0.0f) { ka += ksum / fmaxf(osum, 1.0f); kn += 1.0f; }
    }
    out[0] = rl / fmaxf(rs, 1.0f);
    out[1] = (ka / fmaxf(kn, 1.0f)) * 1e-4f;
}

extern "C" void kernel_launch(void* const* d_in, const int* in_sizes, int n_in,
                              void* d_out, int out_size, void* d_ws, size_t ws_size,
                              hipStream_t stream) {
    const float* sf0 = (const float*)d_in[0];
    const float* sf1 = (const float*)d_in[1];
    const float* tf0 = (const float*)d_in[2];
    const float* tf1 = (const float*)d_in[3];
    const void*  cam = d_in[4];
    const float* eps_prior = (const float*)d_in[5];
    const float* eps_post  = (const float*)d_in[6];
    const float* enc_w1 = (const float*)d_in[7];
    const float* enc_b1 = (const float*)d_in[8];
    const float* ln_g   = (const float*)d_in[9];
    const float* ln_b   = (const float*)d_in[10];
    const float* enc_w2 = (const float*)d_in[11];
    const float* enc_b2 = (const float*)d_in[12];
    const float* prior_w1 = (const float*)d_in[13];
    const float* prior_b1 = (const float*)d_in[14];
    const float* prior_w2 = (const float*)d_in[15];
    const float* prior_b2 = (const float*)d_in[16];
    const float* post_w1 = (const float*)d_in[17];
    const float* post_b1 = (const float*)d_in[18];
    const float* post_w2 = (const float*)d_in[19];
    const float* post_b2 = (const float*)d_in[20];
    const float* dec_w1 = (const float*)d_in[21];
    const float* dec_b1 = (const float*)d_in[22];
    const float* dec_w2 = (const float*)d_in[23];
    const float* dec_b2 = (const float*)d_in[24];
    const float* gru_wih = (const float*)d_in[25];
    const float* gru_whh = (const float*)d_in[26];
    const float* gru_bih = (const float*)d_in[27];
    const float* gru_bhh = (const float*)d_in[28];

    float* ws = (float*)d_ws;
    float* obs   = ws;                 // 48*768 = 36864
    float* tgt   = ws + 36864;         // 36864
    float* oe    = ws + 73728;         // 48*128 = 6144
    float* maskf = ws + 79872;         // 48
    float* rec   = ws + 79920;         // 48
    float* klv   = ws + 79968;         // 48

    prep_mask<<<1, 64, 0, stream>>>(cam, maskf);
    // 73728 wave-jobs, 4 waves/block -> 18432 blocks
    reduce_feats<<<18432, 256, 0, stream>>>(sf0, sf1, tf0, tf1, obs, tgt);
    encoder<<<48, 128, 0, stream>>>(obs, enc_w1, enc_b1, ln_g, ln_b, enc_w2, enc_b2, oe);
    rssm_scan<<<8, 256, 0, stream>>>(oe, tgt, maskf, eps_prior, eps_post,
                                     prior_w1, prior_b1, prior_w2, prior_b2,
                                     post_w1, post_b1, post_w2, post_b2,
                                     dec_w1, dec_b1, dec_w2, dec_b2,
                                     gru_wih, gru_whh, gru_bih, gru_bhh,
                                     rec, klv);
    finalize<<<1, 64, 0, stream>>>(maskf, rec, klv, (float*)d_out);
}